// Round 17
// baseline (59.106 us; speedup 1.0000x reference)
//
#include <hip/hip_runtime.h>

#define A_COUNT 24576
#define B_COUNT 32
#define NOBJ 16
#define C_COUNT 21

#define NCH 96                      // anchor chunks per batch: CHUNK=256, 1 anchor/thread
#define CHUNK (A_COUNT / NCH)       // 256
#define NBLK (NCH * B_COUNT)        // 3072 blocks / partial slots
#define NROWS (B_COUNT * NOBJ)      // 512
#define TOTAL4 (B_COUNT * A_COUNT * C_COUNT / 4)  // 4128768 float4
#define STRIDE4 (NBLK * 256)        // 786432 ; (*4) mod 21 == 12

// ---- workspace layout (bytes); every slot fully rewritten every call ----
#define WS_BPP 0                    // u64 [NROWS][NCH] = 393216 B
#define WS_LOCP 393216              // f32 [NBLK]
#define WS_CLSP 405504              // f32 [NBLK]
#define WS_POSP 417792              // u32 [NBLK]

__device__ __forceinline__ unsigned long long pack_key(float iou, int a) {
    unsigned int ib = __float_as_uint(iou);  // iou >= 0 so uint order == float order
    return ((unsigned long long)ib << 32) | (unsigned long long)(0xFFFFFFFFu - (unsigned int)a);
}

// fast-rcp IoU: identical inline everywhere -> consistent match decisions
__device__ __forceinline__ float iou_pf(float tx0, float ty0, float tx1, float ty1, float at,
                                        float x0, float y0, float x1, float y1, float ap) {
    float lx = fmaxf(tx0, x0), ly = fmaxf(ty0, y0);
    float rx = fminf(tx1, x1), ry = fminf(ty1, y1);
    float w = fmaxf(rx - lx, 0.0f), h = fmaxf(ry - ly, 0.0f);
    float inter = w * h;
    return inter * __builtin_amdgcn_rcpf(at + ap - inter);
}

__device__ __forceinline__ float sl1(float d) {
    float ad = fabsf(d);
    return (ad < 1.0f) ? 0.5f * d * d : ad - 0.5f;
}

__device__ __forceinline__ float loc_term(float4 t, float4 an, float4 lp) {
    float gx = ((t.x + t.z) * 0.5f - an.x) / (0.1f * an.z);
    float gy = ((t.y + t.w) * 0.5f - an.y) / (0.1f * an.w);
    float gw = __logf((t.z - t.x) / an.z) * 5.0f;
    float gh = __logf((t.w - t.y) / an.w) * 5.0f;
    return sl1(lp.x - gx) + sl1(lp.y - gy) + sl1(lp.z - gw) + sl1(lp.w - gh);
}

// exact focal correction at the matched class column:
// + 0.25*(1-p)^2*(-ln p)  - 0.75*p^2*ln(1+e^x)   (removes the t=0 main term)
__device__ __forceinline__ float corr_term(float x) {
    float E = __expf(x);
    float den = 1.0f + E;
    float s = __builtin_amdgcn_rcpf(den);   // 1-p
    float p = E * s;
    float L = __logf(den);                  // ln(1+e^x); -ln p = L - x
    return 0.25f * s * s * (L - x) - 0.75f * p * p * L;
}

// focal main term (t=0 form, 0.75 hoisted): acc += p^2 * ln(1+e^x) for non-bg
#define FOC(xval, rr, acc) {                                 \
    float E_ = __expf(xval);                                 \
    float den_ = 1.0f + E_;                                  \
    float s_ = __builtin_amdgcn_rcpf(den_);                  \
    float p_ = E_ * s_;                                      \
    float L_ = __logf(den_);                                 \
    float v_ = ((rr) == 0 || (rr) == 21) ? 0.0f : p_ * p_ * L_; \
    acc += v_; }

// Kernel 1 (r12-proven): single IoU pass, one anchor/thread, LDS key tree;
// focal main term with 2-deep load pipeline (MLP=2).
__global__ __launch_bounds__(256, 4) void k_main(const float* __restrict__ cls,
                                                 const float4* __restrict__ locp,
                                                 const float4* __restrict__ anchors,
                                                 const float4* __restrict__ truths,
                                                 const int* __restrict__ labels,
                                                 unsigned long long* __restrict__ bp_partial,
                                                 float* __restrict__ loc_partial,
                                                 float* __restrict__ cls_partial,
                                                 unsigned int* __restrict__ pos_partial) {
    const int ch = blockIdx.x;
    const int b = blockIdx.y;
    const int tid = threadIdx.x;
    __shared__ float4 s_t[NOBJ];
    __shared__ float s_area[NOBJ];
    __shared__ int s_lab[NOBJ];
    __shared__ unsigned long long s_keys[8][256];
    if (tid < NOBJ) {
        float4 t = truths[b * NOBJ + tid];
        s_t[tid] = t;
        s_area[tid] = (t.z - t.x) * (t.w - t.y);
        s_lab[tid] = labels[b * NOBJ + tid];
    }
    __syncthreads();
    const int a0 = ch * CHUNK + tid;         // exactly one anchor per thread
    float4 an0 = anchors[a0];
    float p0x0 = an0.x - an0.z * 0.5f, p0y0 = an0.y - an0.w * 0.5f;
    float p0x1 = an0.x + an0.z * 0.5f, p0y1 = an0.y + an0.w * 0.5f;
    float ap0 = (p0x1 - p0x0) * (p0y1 - p0y0);
    float best0 = -1.0f;
    int idx0 = 0;
#pragma unroll
    for (int half = 0; half < 2; ++half) {
#pragma unroll
        for (int n = 0; n < 8; ++n) {
            const int nt = half * 8 + n;
            float4 t = s_t[nt];
            float at = s_area[nt];
            float iou0 = iou_pf(t.x, t.y, t.z, t.w, at, p0x0, p0y0, p0x1, p0y1, ap0);
            if (iou0 > best0) { best0 = iou0; idx0 = nt; }   // first-occurrence argmax
            s_keys[n][tid] = pack_key(iou0, a0);
        }
        __syncthreads();
        if (tid < 128) {
            const int g = tid >> 4, l = tid & 15;
            unsigned long long k = s_keys[g][l];
#pragma unroll
            for (int kk = 1; kk < 16; ++kk) {
                unsigned long long v = s_keys[g][l + 16 * kk];
                k = (v > k) ? v : k;
            }
#pragma unroll
            for (int s = 8; s >= 1; s >>= 1) {
                unsigned long long o = __shfl_xor(k, s);
                k = (o > k) ? o : k;
            }
            if (l == 0) bp_partial[(b * NOBJ + half * 8 + g) * NCH + ch] = k;
        }
        __syncthreads();
    }
    // per-anchor pre-override contribution (rare)
    float loc_l = 0.0f, corr_acc = 0.0f;
    unsigned int pos = 0;
    if (!(best0 < 0.5f)) {
        pos = 1;
        loc_l = loc_term(s_t[idx0], an0, locp[(size_t)b * A_COUNT + a0]);
        corr_acc = corr_term(cls[((size_t)b * A_COUNT + a0) * C_COUNT + s_lab[idx0]]);
    }

    // focal main term, coalesced float4 stream, 2-deep pipeline (MLP=2)
    const int bid = b * NCH + ch;
    float cls_acc;
    {
        const float4* cls4 = (const float4*)cls;
        int i = bid * 256 + tid;                 // < STRIDE4, always valid
        unsigned int f = (unsigned int)i * 4u;
        unsigned int dq = f / 21u;
        int r = (int)(f - dq * 21u);
        float acc0 = 0.0f, acc1 = 0.0f, acc2 = 0.0f, acc3 = 0.0f;
        float4 cur = cls4[i];
        for (;;) {
            const int inext = i + STRIDE4;
            const bool more = inext < TOTAL4;    // wave-uniform (64-aligned boundary)
            float4 nxt;
            if (more) nxt = cls4[inext];         // in flight while cur is consumed
            FOC(cur.x, r + 0, acc0); FOC(cur.y, r + 1, acc1);
            FOC(cur.z, r + 2, acc2); FOC(cur.w, r + 3, acc3);
            if (!more) break;
            cur = nxt;
            i = inext;
            r += 12; if (r >= 21) r -= 21;       // (STRIDE4*4) mod 21 == 12
        }
        cls_acc = corr_acc + 0.75f * ((acc0 + acc1) + (acc2 + acc3));
    }

#pragma unroll
    for (int s = 32; s >= 1; s >>= 1) {
        loc_l += __shfl_xor(loc_l, s);
        cls_acc += __shfl_xor(cls_acc, s);
        pos += __shfl_xor(pos, s);
    }
    __shared__ float s_ll[4], s_cl[4];
    __shared__ unsigned int s_pp[4];
    if ((tid & 63) == 0) {
        s_ll[tid >> 6] = loc_l;
        s_cl[tid >> 6] = cls_acc;
        s_pp[tid >> 6] = pos;
    }
    __syncthreads();
    if (tid == 0) {
        loc_partial[bid] = s_ll[0] + s_ll[1] + s_ll[2] + s_ll[3];
        cls_partial[bid] = s_cl[0] + s_cl[1] + s_cl[2] + s_cl[3];
        pos_partial[bid] = s_pp[0] + s_pp[1] + s_pp[2] + s_pp[3];
    }
}

// Kernel 2 (single block): bp reduction -> forced-match winner deltas ->
// final double reduction -> out. Merges the old k_fix + k_final.
__global__ __launch_bounds__(256) void k_tail(const float* __restrict__ cls,
                                              const float4* __restrict__ locp,
                                              const float4* __restrict__ anchors,
                                              const float4* __restrict__ truths,
                                              const int* __restrict__ labels,
                                              const unsigned long long* __restrict__ bp_partial,
                                              const float* __restrict__ loc_partial,
                                              const float* __restrict__ cls_partial,
                                              const unsigned int* __restrict__ pos_partial,
                                              float* __restrict__ out) {
    const int tid = threadIdx.x;
    __shared__ int s_bp[NROWS];
    // Phase A: global best prior per (b,n) row; 16 lanes/row, 16 rows in flight
    {
        const int g = tid >> 4, l = tid & 15;
        for (int base = 0; base < NROWS; base += 16) {
            const int row = base + g;
            const unsigned long long* pp = &bp_partial[(size_t)row * NCH];
            unsigned long long k = pp[l];
#pragma unroll
            for (int kk = 1; kk < 6; ++kk) {             // 96 = 6 x 16
                unsigned long long v = pp[l + 16 * kk];
                k = (v > k) ? v : k;
            }
#pragma unroll
            for (int s = 8; s >= 1; s >>= 1) {
                unsigned long long o = __shfl_xor(k, s);
                k = (o > k) ? o : k;
            }
            if (l == 0) {
                unsigned int ia = 0xFFFFFFFFu - (unsigned int)(k & 0xFFFFFFFFull);
                s_bp[row] = (ia >= A_COUNT) ? -1 : (int)ia;
            }
        }
    }
    __syncthreads();

    // Phase B: winner per forced anchor (last n wins), exact delta corrections
    // via recompute identical in order/math to k_main.
    float d_loc = 0.0f, d_cls = 0.0f;
    int d_pos = 0;
    for (int pr = tid; pr < NROWS; pr += 256) {
        const int b2 = pr >> 4, n = pr & 15;
        const int q = s_bp[pr];
        bool winner = (q >= 0);
        for (int n2 = n + 1; n2 < NOBJ; ++n2)
            if (s_bp[(b2 << 4) | n2] == q) winner = false;    // later truth wins
        if (!winner) continue;
        float4 an = anchors[q];
        float px0 = an.x - an.z * 0.5f, py0 = an.y - an.w * 0.5f;
        float px1 = an.x + an.z * 0.5f, py1 = an.y + an.w * 0.5f;
        float ap = (px1 - px0) * (py1 - py0);
        float best = -1.0f;
        int idx = 0;
        for (int n2 = 0; n2 < NOBJ; ++n2) {
            float4 t = truths[b2 * NOBJ + n2];
            float at = (t.z - t.x) * (t.w - t.y);
            float iou = iou_pf(t.x, t.y, t.z, t.w, at, px0, py0, px1, py1, ap);
            if (iou > best) { best = iou; idx = n2; }
        }
        float4 lp = locp[(size_t)b2 * A_COUNT + q];
        if (!(best < 0.5f)) {                            // remove original contribution
            d_pos -= 1;
            d_loc -= loc_term(truths[b2 * NOBJ + idx], an, lp);
            d_cls -= corr_term(cls[((size_t)b2 * A_COUNT + q) * C_COUNT + labels[b2 * NOBJ + idx]]);
        }
        d_pos += 1;                                      // add forced contribution
        d_loc += loc_term(truths[b2 * NOBJ + n], an, lp);
        d_cls += corr_term(cls[((size_t)b2 * A_COUNT + q) * C_COUNT + labels[b2 * NOBJ + n]]);
    }

    // Phase C: deterministic final reduction in double
    double loc = (double)d_loc, clsv = (double)d_cls;
    int pos = d_pos;
    for (int i = tid; i < NBLK; i += 256) {
        loc += (double)loc_partial[i];
        clsv += (double)cls_partial[i];
        pos += (int)pos_partial[i];
    }
#pragma unroll
    for (int s = 32; s >= 1; s >>= 1) {
        loc += __shfl_xor(loc, s);
        clsv += __shfl_xor(clsv, s);
        pos += __shfl_xor(pos, s);
    }
    __shared__ double s_l[4], s_c[4];
    __shared__ int s_p[4];
    if ((tid & 63) == 0) {
        s_l[tid >> 6] = loc;
        s_c[tid >> 6] = clsv;
        s_p[tid >> 6] = pos;
    }
    __syncthreads();
    if (tid == 0) {
        double L = s_l[0] + s_l[1] + s_l[2] + s_l[3];
        double Cv = s_c[0] + s_c[1] + s_c[2] + s_c[3];
        float nm = (float)(s_p[0] + s_p[1] + s_p[2] + s_p[3]);
        float cf = (float)Cv / nm;
        float lf = (float)L / nm;
        out[0] = cf;
        out[1] = lf;
        out[2] = cf + lf;
    }
}

extern "C" void kernel_launch(void* const* d_in, const int* in_sizes, int n_in,
                              void* d_out, int out_size, void* d_ws, size_t ws_size,
                              hipStream_t stream) {
    const float* cls = (const float*)d_in[0];
    const float4* locp = (const float4*)d_in[1];
    const float4* truths = (const float4*)d_in[2];
    const float4* anchors = (const float4*)d_in[3];
    const int* labels = (const int*)d_in[4];

    char* ws = (char*)d_ws;
    unsigned long long* bp_partial = (unsigned long long*)(ws + WS_BPP);
    float* loc_partial = (float*)(ws + WS_LOCP);
    float* cls_partial = (float*)(ws + WS_CLSP);
    unsigned int* pos_partial = (unsigned int*)(ws + WS_POSP);

    k_main<<<dim3(NCH, B_COUNT), 256, 0, stream>>>(cls, locp, anchors, truths, labels,
                                                   bp_partial, loc_partial, cls_partial, pos_partial);
    k_tail<<<1, 256, 0, stream>>>(cls, locp, anchors, truths, labels, bp_partial,
                                  loc_partial, cls_partial, pos_partial, (float*)d_out);
}

// Round 18
// 41.476 us; speedup vs baseline: 1.4251x; 1.4251x over previous
//
#include <hip/hip_runtime.h>

#define A_COUNT 24576
#define B_COUNT 32
#define NOBJ 16
#define C_COUNT 21

#define NCH 96                      // anchor chunks per batch: CHUNK=256, 1 anchor/thread
#define CHUNK (A_COUNT / NCH)       // 256
#define NBLK (NCH * B_COUNT)        // 3072 blocks / partial slots
#define TOTAL4 (B_COUNT * A_COUNT * C_COUNT / 4)  // 4128768 float4
#define STRIDE4 (NBLK * 256)        // 786432

// ---- workspace layout (bytes); every slot fully rewritten every call ----
#define WS_BPP 0                    // u64 [B*NOBJ][NCH] = 393216 B
#define WS_LOCP 393216              // f32 [NBLK]
#define WS_CLSP 405504              // f32 [NBLK]
#define WS_POSP 417792              // u32 [NBLK]
#define WS_DLOC 430080              // f32 [B_COUNT]
#define WS_DCLS 430208              // f32 [B_COUNT]
#define WS_DPOS 430336              // i32 [B_COUNT]

__device__ __forceinline__ unsigned long long pack_key(float iou, int a) {
    unsigned int ib = __float_as_uint(iou);  // iou >= 0 so uint order == float order
    return ((unsigned long long)ib << 32) | (unsigned long long)(0xFFFFFFFFu - (unsigned int)a);
}

// fast-rcp IoU: identical inline everywhere -> consistent match decisions
__device__ __forceinline__ float iou_pf(float tx0, float ty0, float tx1, float ty1, float at,
                                        float x0, float y0, float x1, float y1, float ap) {
    float lx = fmaxf(tx0, x0), ly = fmaxf(ty0, y0);
    float rx = fminf(tx1, x1), ry = fminf(ty1, y1);
    float w = fmaxf(rx - lx, 0.0f), h = fmaxf(ry - ly, 0.0f);
    float inter = w * h;
    return inter * __builtin_amdgcn_rcpf(at + ap - inter);
}

__device__ __forceinline__ float sl1(float d) {
    float ad = fabsf(d);
    return (ad < 1.0f) ? 0.5f * d * d : ad - 0.5f;
}

__device__ __forceinline__ float loc_term(float4 t, float4 an, float4 lp) {
    float gx = ((t.x + t.z) * 0.5f - an.x) / (0.1f * an.z);
    float gy = ((t.y + t.w) * 0.5f - an.y) / (0.1f * an.w);
    float gw = __logf((t.z - t.x) / an.z) * 5.0f;
    float gh = __logf((t.w - t.y) / an.w) * 5.0f;
    return sl1(lp.x - gx) + sl1(lp.y - gy) + sl1(lp.z - gw) + sl1(lp.w - gh);
}

// exact focal correction at the matched class column:
// + 0.25*(1-p)^2*(-ln p)  - 0.75*p^2*ln(1+e^x)   (removes the t=0 main term)
__device__ __forceinline__ float corr_term(float x) {
    float E = __expf(x);
    float den = 1.0f + E;
    float s = __builtin_amdgcn_rcpf(den);   // 1-p
    float p = E * s;
    float L = __logf(den);                  // ln(1+e^x); -ln p = L - x
    return 0.25f * s * s * (L - x) - 0.75f * p * p * L;
}

// focal main term (t=0 form, 0.75 hoisted): acc += p^2 * ln(1+e^x) for non-bg
#define FOC(xval, rr, acc) {                                 \
    float E_ = __expf(xval);                                 \
    float den_ = 1.0f + E_;                                  \
    float s_ = __builtin_amdgcn_rcpf(den_);                  \
    float p_ = E_ * s_;                                      \
    float L_ = __logf(den_);                                 \
    float v_ = ((rr) == 0 || (rr) == 21) ? 0.0f : p_ * p_ * L_; \
    acc += v_; }

// Kernel 1: single IoU pass, ONE anchor per thread (uniform waves):
// per-truth block argmax -> bp_partial; per-anchor match -> pre-override
// loc/corr/pos partials; then grid-stride focal main term.
__global__ __launch_bounds__(256, 4) void k_main(const float* __restrict__ cls,
                                                 const float4* __restrict__ locp,
                                                 const float4* __restrict__ anchors,
                                                 const float4* __restrict__ truths,
                                                 const int* __restrict__ labels,
                                                 unsigned long long* __restrict__ bp_partial,
                                                 float* __restrict__ loc_partial,
                                                 float* __restrict__ cls_partial,
                                                 unsigned int* __restrict__ pos_partial) {
    const int ch = blockIdx.x;
    const int b = blockIdx.y;
    const int tid = threadIdx.x;
    __shared__ float4 s_t[NOBJ];
    __shared__ float s_area[NOBJ];
    __shared__ int s_lab[NOBJ];
    __shared__ unsigned long long s_keys[8][256];
    if (tid < NOBJ) {
        float4 t = truths[b * NOBJ + tid];
        s_t[tid] = t;
        s_area[tid] = (t.z - t.x) * (t.w - t.y);
        s_lab[tid] = labels[b * NOBJ + tid];
    }
    __syncthreads();
    const int a0 = ch * CHUNK + tid;         // exactly one anchor per thread
    float4 an0 = anchors[a0];
    float p0x0 = an0.x - an0.z * 0.5f, p0y0 = an0.y - an0.w * 0.5f;
    float p0x1 = an0.x + an0.z * 0.5f, p0y1 = an0.y + an0.w * 0.5f;
    float ap0 = (p0x1 - p0x0) * (p0y1 - p0y0);
    float best0 = -1.0f;
    int idx0 = 0;
#pragma unroll
    for (int half = 0; half < 2; ++half) {
#pragma unroll
        for (int n = 0; n < 8; ++n) {
            const int nt = half * 8 + n;
            float4 t = s_t[nt];
            float at = s_area[nt];
            float iou0 = iou_pf(t.x, t.y, t.z, t.w, at, p0x0, p0y0, p0x1, p0y1, ap0);
            if (iou0 > best0) { best0 = iou0; idx0 = nt; }   // first-occurrence argmax
            s_keys[n][tid] = pack_key(iou0, a0);
        }
        __syncthreads();
        if (tid < 128) {
            const int g = tid >> 4, l = tid & 15;
            unsigned long long k = s_keys[g][l];
#pragma unroll
            for (int kk = 1; kk < 16; ++kk) {
                unsigned long long v = s_keys[g][l + 16 * kk];
                k = (v > k) ? v : k;
            }
#pragma unroll
            for (int s = 8; s >= 1; s >>= 1) {
                unsigned long long o = __shfl_xor(k, s);
                k = (o > k) ? o : k;
            }
            if (l == 0) bp_partial[(b * NOBJ + half * 8 + g) * NCH + ch] = k;
        }
        __syncthreads();
    }
    // per-anchor pre-override contribution (rare)
    float loc_l = 0.0f, corr_acc = 0.0f;
    unsigned int pos = 0;
    if (!(best0 < 0.5f)) {
        pos = 1;
        loc_l = loc_term(s_t[idx0], an0, locp[(size_t)b * A_COUNT + a0]);
        corr_acc = corr_term(cls[((size_t)b * A_COUNT + a0) * C_COUNT + s_lab[idx0]]);
    }

    // focal main term for ALL non-background logits, coalesced float4 stream
    const int bid = b * NCH + ch;
    float cls_acc;
    {
        const float4* cls4 = (const float4*)cls;
        int i = bid * 256 + tid;
        unsigned int f = (unsigned int)i * 4u;
        unsigned int dq = f / 21u;
        int r = (int)(f - dq * 21u);
        float acc0 = 0.0f, acc1 = 0.0f, acc2 = 0.0f, acc3 = 0.0f;
        for (; i < TOTAL4; i += STRIDE4) {
            float4 x4 = cls4[i];
            FOC(x4.x, r + 0, acc0); FOC(x4.y, r + 1, acc1);
            FOC(x4.z, r + 2, acc2); FOC(x4.w, r + 3, acc3);
            r += 12; if (r >= 21) r -= 21;  // (STRIDE4*4) mod 21 == 12
        }
        cls_acc = corr_acc + 0.75f * ((acc0 + acc1) + (acc2 + acc3));
    }

#pragma unroll
    for (int s = 32; s >= 1; s >>= 1) {
        loc_l += __shfl_xor(loc_l, s);
        cls_acc += __shfl_xor(cls_acc, s);
        pos += __shfl_xor(pos, s);
    }
    __shared__ float s_ll[4], s_cl[4];
    __shared__ unsigned int s_pp[4];
    if ((tid & 63) == 0) {
        s_ll[tid >> 6] = loc_l;
        s_cl[tid >> 6] = cls_acc;
        s_pp[tid >> 6] = pos;
    }
    __syncthreads();
    if (tid == 0) {
        loc_partial[bid] = s_ll[0] + s_ll[1] + s_ll[2] + s_ll[3];
        cls_partial[bid] = s_cl[0] + s_cl[1] + s_cl[2] + s_cl[3];
        pos_partial[bid] = s_pp[0] + s_pp[1] + s_pp[2] + s_pp[3];
    }
}

// Kernel 2: one block per batch: reduce bp_partial rows (96 wide), forced-match
// winners (last n wins), exact delta corrections via identical recompute.
__global__ __launch_bounds__(256) void k_fix(const float* __restrict__ cls,
                                             const float4* __restrict__ locp,
                                             const float4* __restrict__ anchors,
                                             const float4* __restrict__ truths,
                                             const int* __restrict__ labels,
                                             const unsigned long long* __restrict__ bp_partial,
                                             float* __restrict__ dloc,
                                             float* __restrict__ dcls,
                                             int* __restrict__ dpos) {
    const int b = blockIdx.x;
    const int tid = threadIdx.x;
    __shared__ int s_bp[NOBJ];
    {   // 16 rows x 16 lanes: global best prior per (b,n)
        const int g = tid >> 4, l = tid & 15;
        const unsigned long long* pp = &bp_partial[(size_t)(b * NOBJ + g) * NCH];
        unsigned long long k = pp[l];
#pragma unroll
        for (int kk = 1; kk < 6; ++kk) {                 // 96 = 6 x 16
            unsigned long long v = pp[l + 16 * kk];
            k = (v > k) ? v : k;
        }
#pragma unroll
        for (int s = 8; s >= 1; s >>= 1) {
            unsigned long long o = __shfl_xor(k, s);
            k = (o > k) ? o : k;
        }
        if (l == 0) {
            unsigned int ia = 0xFFFFFFFFu - (unsigned int)(k & 0xFFFFFFFFull);
            s_bp[g] = (ia >= A_COUNT) ? -1 : (int)ia;
        }
    }
    __syncthreads();
    float d_loc = 0.0f, d_cls = 0.0f;
    int d_pos = 0;
    if (tid < NOBJ) {
        const int n = tid;
        const int q = s_bp[n];
        bool winner = (q >= 0);
        for (int n2 = n + 1; n2 < NOBJ; ++n2)
            if (s_bp[n2] == q) winner = false;           // later truth wins the anchor
        if (winner) {
            float4 an = anchors[q];
            float px0 = an.x - an.z * 0.5f, py0 = an.y - an.w * 0.5f;
            float px1 = an.x + an.z * 0.5f, py1 = an.y + an.w * 0.5f;
            float ap = (px1 - px0) * (py1 - py0);
            float best = -1.0f;
            int idx = 0;
            for (int n2 = 0; n2 < NOBJ; ++n2) {          // identical order/math as k_main
                float4 t = truths[b * NOBJ + n2];
                float at = (t.z - t.x) * (t.w - t.y);
                float iou = iou_pf(t.x, t.y, t.z, t.w, at, px0, py0, px1, py1, ap);
                if (iou > best) { best = iou; idx = n2; }
            }
            float4 lp = locp[(size_t)b * A_COUNT + q];
            if (!(best < 0.5f)) {                        // remove original contribution
                d_pos -= 1;
                d_loc -= loc_term(truths[b * NOBJ + idx], an, lp);
                d_cls -= corr_term(cls[((size_t)b * A_COUNT + q) * C_COUNT + labels[b * NOBJ + idx]]);
            }
            d_pos += 1;                                  // add forced contribution
            d_loc += loc_term(truths[b * NOBJ + n], an, lp);
            d_cls += corr_term(cls[((size_t)b * A_COUNT + q) * C_COUNT + labels[b * NOBJ + n]]);
        }
    }
    if (tid < 64) {                                      // lanes 16..63 carry zeros
#pragma unroll
        for (int s = 8; s >= 1; s >>= 1) {
            d_loc += __shfl_xor(d_loc, s);
            d_cls += __shfl_xor(d_cls, s);
            d_pos += __shfl_xor(d_pos, s);
        }
        if (tid == 0) {
            dloc[b] = d_loc;
            dcls[b] = d_cls;
            dpos[b] = d_pos;
        }
    }
}

// Kernel 3: deterministic final reduction in double.
__global__ __launch_bounds__(256) void k_final(const float* __restrict__ loc_partial,
                                               const float* __restrict__ cls_partial,
                                               const unsigned int* __restrict__ pos_partial,
                                               const float* __restrict__ dloc,
                                               const float* __restrict__ dcls,
                                               const int* __restrict__ dpos,
                                               float* __restrict__ out) {
    const int tid = threadIdx.x;
    double loc = 0.0, clsv = 0.0;
    int pos = 0;
    for (int i = tid; i < NBLK; i += 256) {
        loc += (double)loc_partial[i];
        clsv += (double)cls_partial[i];
        pos += (int)pos_partial[i];
    }
    if (tid < B_COUNT) {
        loc += (double)dloc[tid];
        clsv += (double)dcls[tid];
        pos += dpos[tid];
    }
#pragma unroll
    for (int s = 32; s >= 1; s >>= 1) {
        loc += __shfl_xor(loc, s);
        clsv += __shfl_xor(clsv, s);
        pos += __shfl_xor(pos, s);
    }
    __shared__ double s_l[4], s_c[4];
    __shared__ int s_p[4];
    if ((tid & 63) == 0) {
        s_l[tid >> 6] = loc;
        s_c[tid >> 6] = clsv;
        s_p[tid >> 6] = pos;
    }
    __syncthreads();
    if (tid == 0) {
        double L = s_l[0] + s_l[1] + s_l[2] + s_l[3];
        double Cv = s_c[0] + s_c[1] + s_c[2] + s_c[3];
        float nm = (float)(s_p[0] + s_p[1] + s_p[2] + s_p[3]);
        float cf = (float)Cv / nm;
        float lf = (float)L / nm;
        out[0] = cf;
        out[1] = lf;
        out[2] = cf + lf;
    }
}

extern "C" void kernel_launch(void* const* d_in, const int* in_sizes, int n_in,
                              void* d_out, int out_size, void* d_ws, size_t ws_size,
                              hipStream_t stream) {
    const float* cls = (const float*)d_in[0];
    const float4* locp = (const float4*)d_in[1];
    const float4* truths = (const float4*)d_in[2];
    const float4* anchors = (const float4*)d_in[3];
    const int* labels = (const int*)d_in[4];

    char* ws = (char*)d_ws;
    unsigned long long* bp_partial = (unsigned long long*)(ws + WS_BPP);
    float* loc_partial = (float*)(ws + WS_LOCP);
    float* cls_partial = (float*)(ws + WS_CLSP);
    unsigned int* pos_partial = (unsigned int*)(ws + WS_POSP);
    float* dloc = (float*)(ws + WS_DLOC);
    float* dcls = (float*)(ws + WS_DCLS);
    int* dpos = (int*)(ws + WS_DPOS);

    k_main<<<dim3(NCH, B_COUNT), 256, 0, stream>>>(cls, locp, anchors, truths, labels,
                                                   bp_partial, loc_partial, cls_partial, pos_partial);
    k_fix<<<B_COUNT, 256, 0, stream>>>(cls, locp, anchors, truths, labels, bp_partial,
                                       dloc, dcls, dpos);
    k_final<<<1, 256, 0, stream>>>(loc_partial, cls_partial, pos_partial, dloc, dcls, dpos,
                                   (float*)d_out);
}